// Round 13
// baseline (216.200 us; speedup 1.0000x reference)
//
#include <hip/hip_runtime.h>
#include <math.h>

#define D_MODEL 768
#define HS 64
#define BATCH 8
#define SEQ 2048
#define SCALE 0.125f
#define KSPLIT 8
#define KCHUNK (SEQ / KSPLIT)   // 256

typedef _Float16 half_t;
typedef __attribute__((ext_vector_type(8))) _Float16 half8;
typedef __attribute__((ext_vector_type(4))) float floatx4;

// async global->LDS, 16B per lane, lane-linear LDS destination
typedef const __attribute__((address_space(1))) void gas_void;
typedef __attribute__((address_space(3))) void las_void;
__device__ __forceinline__ void gl_lds16(const void* g, void* l) {
    __builtin_amdgcn_global_load_lds((gas_void*)g, (las_void*)l, 16, 0, 0);
}
__device__ __forceinline__ void waitcnt_all() {
    __builtin_amdgcn_s_waitcnt(0);
}

// ---------------------------------------------------------------
// Kernel 1: W fp32 [D][H] x3 -> Wt fp16 [3*H][D]; block 0 also
// zeroes the 128 per-group completion counters (re-poison-safe:
// runs every call, stream-ordered before attn).
// ---------------------------------------------------------------
__global__ __launch_bounds__(256)
void wconv_kernel(const float* __restrict__ Wq, const float* __restrict__ Wk,
                  const float* __restrict__ Wv, half_t* __restrict__ Wt,
                  int* __restrict__ cnt)
{
    if (blockIdx.x == 0 && threadIdx.x < BATCH * (SEQ / 128))
        cnt[threadIdx.x] = 0;
    int m = blockIdx.x >> 6;
    int h = blockIdx.x & 63;
    const float* W = (m == 0) ? Wq : ((m == 1) ? Wk : Wv);
    half_t* dst = Wt + (size_t)blockIdx.x * D_MODEL;
    for (int k = threadIdx.x; k < D_MODEL; k += 256)
        dst[k] = (half_t)W[(size_t)k * HS + h];
}

// ---------------------------------------------------------------
// Kernel 2: QKV projection. M=64 x N=192 tile (grid 256), parity
// double-buffered LDS, ONE barrier/iter, register prefetch after
// the barrier (R8/R12-proven).
// ---------------------------------------------------------------
__global__ __launch_bounds__(256)
void proj_kernel(const float* __restrict__ x, const half_t* __restrict__ Wt,
                 const float* __restrict__ bq, const float* __restrict__ bk,
                 const float* __restrict__ bv,
                 half_t* __restrict__ Qh, half_t* __restrict__ Kh,
                 half_t* __restrict__ Vt)
{
    __shared__ __align__(16) half_t xs[2][64 * 64];    // 2 x 8 KB
    __shared__ __align__(16) half_t wt[2][192 * 64];   // 2 x 24 KB

    const int tid = threadIdx.x;
    const int w = tid >> 6;
    const int lane = tid & 63;
    const int l15 = lane & 15;
    const int quad = lane >> 4;
    const long row0 = (long)blockIdx.x * 64;

    floatx4 acc[4][3];
#pragma unroll
    for (int i = 0; i < 4; ++i)
#pragma unroll
        for (int j = 0; j < 3; ++j) acc[i][j] = (floatx4){0.f, 0.f, 0.f, 0.f};

    float4 xA[4], xB[4];
    half8  wA[6], wB[6];

    auto loadx = [&](int k0, float4 (&v)[4]) {
#pragma unroll
        for (int i = 0; i < 2; ++i) {
            int idx = i * 256 + tid;
            int r = idx >> 3, sc = idx & 7;
            int cg = sc ^ (r & 7);
            const float* p = x + (row0 + r) * D_MODEL + k0 + cg * 8;
            v[i * 2]     = *(const float4*)p;
            v[i * 2 + 1] = *(const float4*)(p + 4);
        }
    };
    auto loadw = [&](int k0, half8 (&wr)[6]) {
#pragma unroll
        for (int i = 0; i < 6; ++i) {
            int idx = i * 256 + tid;
            int r = idx >> 3, sc = idx & 7;
            int cg = sc ^ (r & 7);
            wr[i] = *(const half8*)(Wt + (size_t)r * D_MODEL + k0 + cg * 8);
        }
    };

    auto step = [&](int it, float4 (&xc)[4], half8 (&wc)[6],
                    float4 (&xn)[4], half8 (&wn)[6], int p) {
#pragma unroll
        for (int i = 0; i < 2; ++i) {
            float4 a = xc[i * 2], b = xc[i * 2 + 1];
            half8 xh = (half8){(half_t)a.x, (half_t)a.y, (half_t)a.z, (half_t)a.w,
                               (half_t)b.x, (half_t)b.y, (half_t)b.z, (half_t)b.w};
            *(half8*)&xs[p][(i * 256 + tid) * 8] = xh;
        }
#pragma unroll
        for (int i = 0; i < 6; ++i)
            *(half8*)&wt[p][(i * 256 + tid) * 8] = wc[i];
        __syncthreads();
        int kn = (it + 1 < 12) ? (it + 1) * 64 : 0;
        loadx(kn, xn);
        loadw(kn, wn);
#pragma unroll
        for (int kst = 0; kst < 2; ++kst) {
            half8 af[4];
#pragma unroll
            for (int mt = 0; mt < 4; ++mt) {
                int r = mt * 16 + l15;
                int slot = (kst * 4 + quad) ^ (r & 7);
                af[mt] = *(const half8*)&xs[p][r * 64 + slot * 8];
            }
#pragma unroll
            for (int nt = 0; nt < 3; ++nt) {
                int r = w * 48 + nt * 16 + l15;
                int slot = (kst * 4 + quad) ^ (r & 7);
                half8 bf = *(const half8*)&wt[p][r * 64 + slot * 8];
#pragma unroll
                for (int mt = 0; mt < 4; ++mt)
                    acc[mt][nt] = __builtin_amdgcn_mfma_f32_16x16x32_f16(
                        af[mt], bf, acc[mt][nt], 0, 0, 0);
            }
        }
    };

    loadx(0, xA);
    loadw(0, wA);
#pragma unroll
    for (int it = 0; it < 12; it += 2) {
        step(it,     xA, wA, xB, wB, 0);
        step(it + 1, xB, wB, xA, wA, 1);
    }

#pragma unroll
    for (int nt = 0; nt < 3; ++nt) {
        int nbase = w * 48 + nt * 16;
        int mm = nbase >> 6;
        int h = (nbase + l15) & 63;
        const float* bias = (mm == 0) ? bq : ((mm == 1) ? bk : bv);
        float bval = bias[h];
#pragma unroll
        for (int mt = 0; mt < 4; ++mt)
#pragma unroll
            for (int r = 0; r < 4; ++r) {
                long R = row0 + mt * 16 + quad * 4 + r;
                half_t hv = (half_t)(acc[mt][nt][r] + bval);
                if (mm == 0)      Qh[R * HS + h] = hv;
                else if (mm == 1) Kh[R * HS + h] = hv;
                else {
                    long bb = R >> 11, s = R & 2047;
                    Vt[(bb * HS + h) * SEQ + s] = hv;
                }
            }
    }
}

// ---------------------------------------------------------------
// Kernel 3: flash attention + fused combine. 2-wave blocks (128
// thr, 64 q/wave), grid (16,8,8). Per (b,qblk) group: 8 kh-blocks;
// the last to finish (device-scope atomic counter) combines the 8
// partials for its 128 rows. Sum order is the fixed i=0..7 loop ->
// bitwise deterministic regardless of arrival order.
// ---------------------------------------------------------------
__global__ __launch_bounds__(128)
void attn_kernel(const half_t* __restrict__ Qh, const half_t* __restrict__ Kh,
                 const half_t* __restrict__ Vt,
                 half_t* __restrict__ Opart, float* __restrict__ lpart,
                 int* __restrict__ cnt, float* __restrict__ out)
{
    __shared__ __align__(16) half_t ks[64 * 64];      // 8 KB [kk][h] swizzled
    __shared__ __align__(16) half_t vs[64 * 64];      // 8 KB [h][kk] swizzled
    __shared__ __align__(16) half_t ps[2][16][72];    // 4.5 KB per-wave P
    __shared__ int is_last;

    const int tid = threadIdx.x;
    const int w = tid >> 6;
    const int lane = tid & 63;
    const int l15 = lane & 15;
    const int quad = lane >> 4;
    const int b = blockIdx.y;
    const int qblk = blockIdx.x;
    const int q0 = qblk * 128 + w * 64;
    const int kh = blockIdx.z;
    const int kk_begin = kh * KCHUNK;

    const half_t* Kb = Kh + (size_t)b * SEQ * HS;
    const half_t* Vb = Vt + (size_t)b * HS * SEQ;

    half8 qf[4][2];
#pragma unroll
    for (int mt = 0; mt < 4; ++mt)
#pragma unroll
        for (int kst = 0; kst < 2; ++kst) {
            half8 q = *(const half8*)(Qh + ((size_t)b * SEQ + q0 + mt * 16 + l15) * HS
                                      + kst * 32 + quad * 8);
#pragma unroll
            for (int j = 0; j < 8; ++j) q[j] = q[j] * (half_t)SCALE;
            qf[mt][kst] = q;
        }

    floatx4 oacc[4][4];
    float lsum[4][4];
#pragma unroll
    for (int mt = 0; mt < 4; ++mt) {
#pragma unroll
        for (int nt = 0; nt < 4; ++nt) oacc[mt][nt] = (floatx4){0.f, 0.f, 0.f, 0.f};
#pragma unroll
        for (int r = 0; r < 4; ++r) lsum[mt][r] = 0.f;
    }

    for (int it = 0; it < KCHUNK / 64; ++it) {
        const int kk0 = kk_begin + it * 64;
        __syncthreads();   // WAR: previous tile's readers done
#pragma unroll
        for (int i = 0; i < 4; ++i) {
            int idx = i * 128 + tid;
            int r = idx >> 3, sc = idx & 7;
            int cg = sc ^ (r & 7);
            gl_lds16(Kb + (size_t)(kk0 + r) * HS + cg * 8, ks + idx * 8);
            gl_lds16(Vb + (size_t)r * SEQ + kk0 + cg * 8, vs + idx * 8);
        }
        waitcnt_all();     // async LDS writes landed (vmcnt-tracked)
        __syncthreads();   // tiles visible

        half8 vf[4][2];
#pragma unroll
        for (int nt = 0; nt < 4; ++nt)
#pragma unroll
            for (int kst = 0; kst < 2; ++kst) {
                int r = nt * 16 + l15;
                int slot = (kst * 4 + quad) ^ (r & 7);
                vf[nt][kst] = *(const half8*)&vs[r * 64 + slot * 8];
            }

#pragma unroll
        for (int h2 = 0; h2 < 2; ++h2) {
            floatx4 sacc[2][4];
#pragma unroll
            for (int mtl = 0; mtl < 2; ++mtl)
#pragma unroll
                for (int nt = 0; nt < 4; ++nt) sacc[mtl][nt] = (floatx4){0.f, 0.f, 0.f, 0.f};
#pragma unroll
            for (int nt = 0; nt < 4; ++nt)
#pragma unroll
                for (int kst = 0; kst < 2; ++kst) {
                    int r = nt * 16 + l15;
                    int slot = (kst * 4 + quad) ^ (r & 7);
                    half8 kf = *(const half8*)&ks[r * 64 + slot * 8];
#pragma unroll
                    for (int mtl = 0; mtl < 2; ++mtl)
                        sacc[mtl][nt] = __builtin_amdgcn_mfma_f32_16x16x32_f16(
                            qf[h2 * 2 + mtl][kst], kf, sacc[mtl][nt], 0, 0, 0);
                }

#pragma unroll
            for (int mtl = 0; mtl < 2; ++mtl) {
                int mt = h2 * 2 + mtl;
#pragma unroll
                for (int nt = 0; nt < 4; ++nt)
#pragma unroll
                    for (int r = 0; r < 4; ++r) {
                        float pv = __expf(sacc[mtl][nt][r]);
                        lsum[mt][r] += pv;
                        ps[w][quad * 4 + r][nt * 16 + l15] = (half_t)pv;
                    }
                half8 pfr[2];
#pragma unroll
                for (int kst = 0; kst < 2; ++kst)
                    pfr[kst] = *(const half8*)&ps[w][l15][kst * 32 + quad * 8];
#pragma unroll
                for (int nt = 0; nt < 4; ++nt)
#pragma unroll
                    for (int kst = 0; kst < 2; ++kst)
                        oacc[mt][nt] = __builtin_amdgcn_mfma_f32_16x16x32_f16(
                            pfr[kst], vf[nt][kst], oacc[mt][nt], 0, 0, 0);
            }
        }
    }

    // reduce l across the 16 column-lanes of each quad
#pragma unroll
    for (int mt = 0; mt < 4; ++mt)
#pragma unroll
        for (int r = 0; r < 4; ++r) {
            float s = lsum[mt][r];
            s += __shfl_xor(s, 1);
            s += __shfl_xor(s, 2);
            s += __shfl_xor(s, 4);
            s += __shfl_xor(s, 8);
            lsum[mt][r] = s;
        }

    size_t obase = ((size_t)kh * BATCH + b) * SEQ * HS;
#pragma unroll
    for (int mt = 0; mt < 4; ++mt)
#pragma unroll
        for (int nt = 0; nt < 4; ++nt)
#pragma unroll
            for (int r = 0; r < 4; ++r) {
                int row = q0 + mt * 16 + quad * 4 + r;
                Opart[obase + (size_t)row * HS + nt * 16 + l15] = (half_t)oacc[mt][nt][r];
            }
    if (l15 == 0) {
#pragma unroll
        for (int mt = 0; mt < 4; ++mt)
#pragma unroll
            for (int r = 0; r < 4; ++r) {
                int row = q0 + mt * 16 + quad * 4 + r;
                lpart[((size_t)kh * BATCH + b) * SEQ + row] = lsum[mt][r];
            }
    }

    // -------- fused combine: last kh-block of this (b,qblk) group --------
    __threadfence();                       // release our Opart/lpart writes
    if (tid == 0)
        is_last = (atomicAdd(&cnt[b * (SEQ / 128) + qblk], 1) == KSPLIT - 1);
    __syncthreads();
    if (is_last) {
        __threadfence();                   // acquire peers' writes
        const size_t NT = (size_t)BATCH * SEQ * HS;
        const size_t BS = (size_t)BATCH * SEQ;
        const int rbase = qblk * 128;
#pragma unroll
        for (int c = 0; c < 8; ++c) {
            int eidx = (c * 128 + tid) * 8;            // 0..8191, 8-aligned
            int row = rbase + (eidx >> 6);
            int col = eidx & 63;
            size_t e0 = ((size_t)b * SEQ + row) * HS + col;
            float o[8] = {0, 0, 0, 0, 0, 0, 0, 0};
            float l = 0.f;
#pragma unroll
            for (int i = 0; i < KSPLIT; ++i) {
                half8 oi = *(const half8*)(Opart + (size_t)i * NT + e0);
#pragma unroll
                for (int j = 0; j < 8; ++j) o[j] += (float)oi[j];
                l += lpart[(size_t)i * BS + (size_t)b * SEQ + row];
            }
            float inv = 1.f / l;
            float4 a = {o[0] * inv, o[1] * inv, o[2] * inv, o[3] * inv};
            float4 d = {o[4] * inv, o[5] * inv, o[6] * inv, o[7] * inv};
            *(float4*)(out + e0) = a;
            *(float4*)(out + e0 + 4) = d;
        }
    }
}

extern "C" void kernel_launch(void* const* d_in, const int* in_sizes, int n_in,
                              void* d_out, int out_size, void* d_ws, size_t ws_size,
                              hipStream_t stream) {
    const float* x  = (const float*)d_in[0];
    const float* Wq = (const float*)d_in[1];
    const float* bq = (const float*)d_in[2];
    const float* Wk = (const float*)d_in[3];
    const float* bk = (const float*)d_in[4];
    const float* Wv = (const float*)d_in[5];
    const float* bv = (const float*)d_in[6];
    float* out = (float*)d_out;

    const size_t per = (size_t)BATCH * SEQ * HS;      // 1,048,576 elements
    half_t* Qh = (half_t*)d_ws;
    half_t* Kh = Qh + per;
    half_t* Vt = Kh + per;
    half_t* Wt = Vt + per;                            // 147,456 halfs
    half_t* Opart = Wt + 3 * HS * D_MODEL;
    float*  lpart = (float*)(Opart + (size_t)KSPLIT * per);
    int*    cnt   = (int*)(lpart + (size_t)KSPLIT * BATCH * SEQ);  // 128 ints

    wconv_kernel<<<dim3(3 * HS), dim3(256), 0, stream>>>(Wq, Wk, Wv, Wt, cnt);
    proj_kernel<<<dim3(BATCH * SEQ / 64), dim3(256), 0, stream>>>(
        x, Wt, bq, bk, bv, Qh, Kh, Vt);
    attn_kernel<<<dim3(SEQ / 128, BATCH, KSPLIT), dim3(128), 0, stream>>>(
        Qh, Kh, Vt, Opart, lpart, cnt, out);
}